// Round 1
// baseline (5304.835 us; speedup 1.0000x reference)
//
#include <hip/hip_runtime.h>
#include <cstdint>
#include <cstddef>

// Problem constants (from setup_inputs): h [65536,512] fp32; codebooks
// cb0..cb3 with K = 2048,1024,512,256 rows of 512.
// Outputs flat in d_out (fp32): z_q [B,512] | SIDs [B,4] (as float) |
// r_stack [B,4,512] | q_stack [B,4,512].
#define NB 65536
#define ND 512
#define NL 4

// ---------------------------------------------------------------------------
// Codebook transpose: cbT[d][k] = cb[k][d], so the argmin kernel can read
// codeword columns fully coalesced (32 lanes x float4 = 512B consecutive).
// ---------------------------------------------------------------------------
__global__ __launch_bounds__(256) void transpose_kernel(const float* __restrict__ cb,
                                                        float* __restrict__ cbT,
                                                        int K) {
  __shared__ float tile[32][33];
  const int tx = threadIdx.x, ty = threadIdx.y;
  const int d0 = blockIdx.x * 32, k0 = blockIdx.y * 32;
#pragma unroll
  for (int j = 0; j < 32; j += 8)
    tile[ty + j][tx] = cb[(size_t)(k0 + ty + j) * ND + d0 + tx];
  __syncthreads();
#pragma unroll
  for (int j = 0; j < 32; j += 8)
    cbT[(size_t)(d0 + ty + j) * K + k0 + tx] = tile[tx][ty + j];
}

// ---------------------------------------------------------------------------
// Per-codeword squared norms.
// ---------------------------------------------------------------------------
__global__ __launch_bounds__(256) void cnorm_kernel(const float* __restrict__ cb,
                                                    float* __restrict__ cn) {
  const int k = blockIdx.x;
  const float* row = cb + (size_t)k * ND;
  float s = 0.f;
  for (int t = threadIdx.x; t < ND; t += 256) {
    float v = row[t];
    s = fmaf(v, v, s);
  }
#pragma unroll
  for (int off = 32; off >= 1; off >>= 1) s += __shfl_down(s, off, 64);
  __shared__ float ls[4];
  if ((threadIdx.x & 63) == 0) ls[threadIdx.x >> 6] = s;
  __syncthreads();
  if (threadIdx.x == 0) cn[k] = ls[0] + ls[1] + ls[2] + ls[3];
}

// ---------------------------------------------------------------------------
// Distance + argmin kernel (the hot one; fp32 VALU-bound this round).
// Block: 256 threads = 8 row-groups(ty) x 32 col-lanes(tx).
// BM=32 rows staged full-depth in LDS (64 KB -> 2 blocks/CU).
// Thread tile: 4 rows x 8 cols; BN=256 cols per pass; score = ||c||^2 - 2 r.c
// (||r||^2 constant per row, dropped). Tie-break: lowest index (np.argmin).
// ---------------------------------------------------------------------------
template <int KK>
__global__ __launch_bounds__(256) void argmin_kernel(const float4* __restrict__ rsrc4,
                                                     int rstride4,
                                                     const float* __restrict__ cbT,
                                                     const float* __restrict__ cn,
                                                     int* __restrict__ idx_out) {
  __shared__ float r_s[32 * 512];  // 64 KB
  const int tid = threadIdx.x;
  const int tx = tid & 31, ty = tid >> 5;
  const int row0 = blockIdx.x * 32;

  // Stage 32 rows of r into LDS (coalesced float4 loads).
#pragma unroll
  for (int i = 0; i < 16; ++i) {
    int f = i * 256 + tid;  // 0..4095 float4s
    int row = f >> 7, dq = f & 127;
    float4 v = rsrc4[(size_t)(row0 + row) * rstride4 + dq];
    *(float4*)&r_s[row * 512 + dq * 4] = v;
  }
  __syncthreads();

  float bestd[4];
  int bestk[4];
#pragma unroll
  for (int i = 0; i < 4; ++i) {
    bestd[i] = 3.4028235e38f;
    bestk[i] = 0;
  }

  const float4* rrow[4];
#pragma unroll
  for (int i = 0; i < 4; ++i) rrow[i] = (const float4*)&r_s[(ty * 4 + i) * 512];

  for (int kt = 0; kt < KK; kt += 256) {
    float acc[4][8];
#pragma unroll
    for (int i = 0; i < 4; ++i)
#pragma unroll
      for (int j = 0; j < 8; ++j) acc[i][j] = 0.f;

    const float* cA = cbT + kt + 4 * tx;   // cols 4tx..4tx+3
    const float* cB = cA + 128;            // cols 128+4tx..+3

#pragma unroll 2
    for (int dq = 0; dq < 128; ++dq) {
      float4 rv[4];
#pragma unroll
      for (int i = 0; i < 4; ++i) rv[i] = rrow[i][dq];  // LDS broadcast reads
      float4 a[4], b[4];
#pragma unroll
      for (int dd = 0; dd < 4; ++dd) {
        a[dd] = *(const float4*)&cA[(size_t)(4 * dq + dd) * KK];
        b[dd] = *(const float4*)&cB[(size_t)(4 * dq + dd) * KK];
      }
#pragma unroll
      for (int i = 0; i < 4; ++i) {
        const float* rp = (const float*)&rv[i];
#pragma unroll
        for (int dd = 0; dd < 4; ++dd) {
          const float r = rp[dd];
          const float* ap = (const float*)&a[dd];
          const float* bp = (const float*)&b[dd];
          acc[i][0] = fmaf(r, ap[0], acc[i][0]);
          acc[i][1] = fmaf(r, ap[1], acc[i][1]);
          acc[i][2] = fmaf(r, ap[2], acc[i][2]);
          acc[i][3] = fmaf(r, ap[3], acc[i][3]);
          acc[i][4] = fmaf(r, bp[0], acc[i][4]);
          acc[i][5] = fmaf(r, bp[1], acc[i][5]);
          acc[i][6] = fmaf(r, bp[2], acc[i][6]);
          acc[i][7] = fmaf(r, bp[3], acc[i][7]);
        }
      }
    }

    // Scores + running argmin (cols ascending within thread; strict < keeps
    // the earliest index).
#pragma unroll
    for (int jj = 0; jj < 8; ++jj) {
      const int col = kt + ((jj < 4) ? (4 * tx + jj) : (128 + 4 * tx + jj - 4));
      const float cnv = cn[col];
#pragma unroll
      for (int i = 0; i < 4; ++i) {
        float s = fmaf(-2.f, acc[i][jj], cnv);
        if (s < bestd[i]) {
          bestd[i] = s;
          bestk[i] = col;
        }
      }
    }
  }

  // Reduce across the 32 tx-lanes (each 32-lane half-wave shares ty).
#pragma unroll
  for (int off = 16; off >= 1; off >>= 1) {
#pragma unroll
    for (int i = 0; i < 4; ++i) {
      float od = __shfl_xor(bestd[i], off, 32);
      int ok = __shfl_xor(bestk[i], off, 32);
      if (od < bestd[i] || (od == bestd[i] && ok < bestk[i])) {
        bestd[i] = od;
        bestk[i] = ok;
      }
    }
  }
  if (tx == 0) {
#pragma unroll
    for (int i = 0; i < 4; ++i) idx_out[row0 + ty * 4 + i] = bestk[i];
  }
}

// ---------------------------------------------------------------------------
// Per-level update: q = cb[idx]; write q_stack slot, r_stack slot(s), SIDs;
// last level writes z_q = h - r3 + q3.
// ---------------------------------------------------------------------------
__global__ __launch_bounds__(256) void update_kernel(int level,
                                                     const float4* __restrict__ rsrc4,
                                                     int rstride4,
                                                     const float4* __restrict__ cb4,
                                                     const int* __restrict__ idxp,
                                                     const float4* __restrict__ h4,
                                                     float4* __restrict__ qst4,
                                                     float4* __restrict__ rst4,
                                                     float4* __restrict__ zq4,
                                                     float* __restrict__ sid) {
  const int g = blockIdx.x * 256 + threadIdx.x;  // float4 id over [B, 128]
  const int b = g >> 7, dq = g & 127;
  const int k = idxp[b];
  float4 r = rsrc4[(size_t)b * rstride4 + dq];
  float4 q = cb4[(size_t)k * 128 + dq];
  qst4[(size_t)(b * 4 + level) * 128 + dq] = q;
  if (level == 0) rst4[(size_t)b * 512 + dq] = r;  // r_stack slot 0 = h
  if (level < 3) {
    float4 rn{r.x - q.x, r.y - q.y, r.z - q.z, r.w - q.w};
    rst4[(size_t)(b * 4 + level + 1) * 128 + dq] = rn;
  } else {
    float4 h = h4[(size_t)b * 128 + dq];
    float4 z{h.x - r.x + q.x, h.y - r.y + q.y, h.z - r.z + q.z, h.w - r.w + q.w};
    zq4[(size_t)b * 128 + dq] = z;
  }
  if (dq == 0) sid[b * 4 + level] = (float)k;
}

// ---------------------------------------------------------------------------
extern "C" void kernel_launch(void* const* d_in, const int* in_sizes, int n_in,
                              void* d_out, int out_size, void* d_ws, size_t ws_size,
                              hipStream_t stream) {
  const float* h = (const float*)d_in[0];
  const float* cb[4] = {(const float*)d_in[1], (const float*)d_in[2],
                        (const float*)d_in[3], (const float*)d_in[4]};
  static const int K[4] = {2048, 1024, 512, 256};

  float* out = (float*)d_out;
  float* zq = out;                                  // [B,512]
  float* sid = out + (size_t)NB * ND;               // [B,4]
  float* rst = sid + (size_t)NB * NL;               // [B,4,512]
  float* qst = rst + (size_t)NB * NL * ND;          // [B,4,512]

  // Workspace layout (~8.6 MB): idx[4][B] int | cn[4096] f32 | cbT (7.5 MB)
  int* idx_ws = (int*)d_ws;
  float* cn_ws = (float*)d_ws + (size_t)NL * NB;
  float* cbT_ws = cn_ws + 4096;
  float* cbT[4];
  float* cn[4];
  int* idx[4];
  {
    size_t off = 0;
    int cno = 0;
    for (int l = 0; l < 4; ++l) {
      cbT[l] = cbT_ws + off;
      off += (size_t)ND * K[l];
      cn[l] = cn_ws + cno;
      cno += K[l];
      idx[l] = idx_ws + (size_t)l * NB;
    }
  }

  for (int l = 0; l < 4; ++l) {
    transpose_kernel<<<dim3(ND / 32, K[l] / 32), dim3(32, 8), 0, stream>>>(cb[l], cbT[l], K[l]);
    cnorm_kernel<<<K[l], 256, 0, stream>>>(cb[l], cn[l]);
  }

  const float4* h4 = (const float4*)h;
  float4* qst4 = (float4*)qst;
  float4* rst4 = (float4*)rst;
  float4* zq4 = (float4*)zq;

  for (int l = 0; l < 4; ++l) {
    const float4* rsrc4 = (l == 0) ? h4 : ((const float4*)rst + (size_t)l * 128);
    const int rstride4 = (l == 0) ? 128 : 512;
    switch (K[l]) {
      case 2048:
        argmin_kernel<2048><<<NB / 32, 256, 0, stream>>>(rsrc4, rstride4, cbT[l], cn[l], idx[l]);
        break;
      case 1024:
        argmin_kernel<1024><<<NB / 32, 256, 0, stream>>>(rsrc4, rstride4, cbT[l], cn[l], idx[l]);
        break;
      case 512:
        argmin_kernel<512><<<NB / 32, 256, 0, stream>>>(rsrc4, rstride4, cbT[l], cn[l], idx[l]);
        break;
      default:
        argmin_kernel<256><<<NB / 32, 256, 0, stream>>>(rsrc4, rstride4, cbT[l], cn[l], idx[l]);
        break;
    }
    update_kernel<<<(NB * (ND / 4)) / 256, 256, 0, stream>>>(l, rsrc4, rstride4,
                                                             (const float4*)cb[l], idx[l], h4,
                                                             qst4, rst4, zq4, sid);
  }
}